// Round 1
// baseline (641.726 us; speedup 1.0000x reference)
//
#include <hip/hip_runtime.h>
#include <stdint.h>

#define NB 8
#define F_IN 6300
#define NT 500
#define HID 32
#define NOUT 20

// float32 constants, rounded exactly as np.float32 would round the doubles
#define D_SR   0.7788007830714049f     // exp(-1/4)
#define S_SR   0.6795704571147613f     // e/4
#define D_REF  0.36787944117144233f    // exp(-1)
#define C_REF  -5.43656365691809f      // -2*e

// ---------------- K1: layer 1  (psp(x) -> spike) in exact-order f32 ----------------
// One thread per (b,f) channel; sequential over t. Writes spike bytes s1[b][t][f].
__device__ __forceinline__ void l1_step4(float4 v, float& z1, float& y1, float& zr, float& yr,
                                         uint8_t*& sp) {
  float xs[4] = {v.x, v.y, v.z, v.w};
#pragma unroll
  for (int e = 0; e < 4; e++) {
    y1 = __fmul_rn(D_SR, __fadd_rn(y1, z1));          // y = d*(y+z)
    z1 = __fadd_rn(__fmul_rn(D_SR, z1), xs[e]);       // z = d*z + x
    float p = __fmul_rn(S_SR, y1);                    // psp = scale*y
    yr = __fmul_rn(D_REF, __fadd_rn(yr, zr));         // refractory alpha
    float u = __fadd_rn(p, __fmul_rn(C_REF, yr));     // u = p + C*y
    uint8_t s = (u >= 1.0f) ? 1 : 0;
    zr = __fadd_rn(__fmul_rn(D_REF, zr), s ? 1.0f : 0.0f);
    *sp = s;
    sp += F_IN;
  }
}

__global__ __launch_bounds__(64) void k1_layer1(const float* __restrict__ x,
                                                uint8_t* __restrict__ s1) {
  int id = blockIdx.x * 64 + threadIdx.x;
  if (id >= NB * F_IN) return;
  int b = id / F_IN;
  int f = id - b * F_IN;
  const float4* xr = (const float4*)(x + (size_t)id * NT);
  uint8_t* sp = s1 + (size_t)b * NT * F_IN + f;

  float z1 = 0.f, y1 = 0.f, zr = 0.f, yr = 0.f;
  // software pipeline: keep one 16-t chunk (4 x float4) in flight
  float4 A0 = xr[0], A1 = xr[1], A2 = xr[2], A3 = xr[3];
  int t0 = 0;
  for (int it = 0; it < 30; it++, t0 += 16) {
    int nx = (t0 >> 2) + 4;
    float4 B0 = xr[nx], B1 = xr[nx + 1], B2 = xr[nx + 2], B3 = xr[nx + 3];
    l1_step4(A0, z1, y1, zr, yr, sp);
    l1_step4(A1, z1, y1, zr, yr, sp);
    l1_step4(A2, z1, y1, zr, yr, sp);
    l1_step4(A3, z1, y1, zr, yr, sp);
    A0 = B0; A1 = B1; A2 = B2; A3 = B3;
  }
  // t0 == 480 here; A holds t 480..495, last chunk is t 496..499
  float4 C0 = xr[124];
  l1_step4(A0, z1, y1, zr, yr, sp);
  l1_step4(A1, z1, y1, zr, yr, sp);
  l1_step4(A2, z1, y1, zr, yr, sp);
  l1_step4(A3, z1, y1, zr, yr, sp);
  l1_step4(C0, z1, y1, zr, yr, sp);
}

// ---------------- K2: R[b,o,t] = sum_f w1[o,f] * s1[b,t,f]  (f64 accum) ----------------
// block = 32 o x 8 t ; wave-uniform skip of all-zero 4-byte groups (~66% skipped at 5% density)
__global__ __launch_bounds__(256) void k2_fc1(const float* __restrict__ w1,
                                              const uint8_t* __restrict__ s1,
                                              double* __restrict__ R) {
  int o = threadIdx.x & 31;
  int t = blockIdx.y * 8 + (threadIdx.x >> 5);
  int b = blockIdx.x;
  if (t >= NT) return;
  const uint8_t* row = s1 + (size_t)(b * NT + t) * F_IN;
  const float* wr = w1 + o * F_IN;
  double acc = 0.0;
  for (int f = 0; f < F_IN; f += 4) {
    uint32_t m = *(const uint32_t*)(row + f);
    if (__any(m != 0)) {
      float4 w = *(const float4*)(wr + f);
      if (m & 0x000000FFu) acc += (double)w.x;
      if (m & 0x0000FF00u) acc += (double)w.y;
      if (m & 0x00FF0000u) acc += (double)w.z;
      if (m & 0xFF000000u) acc += (double)w.w;
    }
  }
  R[((size_t)b * HID + o) * NT + t] = acc;
}

// ---------------- K3: layer-2 psp (filter R) + spike -> s2 bytes [b][t][h] ----------------
__global__ __launch_bounds__(256) void k3_spike2(const double* __restrict__ R,
                                                 uint8_t* __restrict__ s2) {
  int id = threadIdx.x;              // exactly NB*HID = 256
  int b = id >> 5, h = id & 31;
  const double* r = R + (size_t)id * NT;
  uint8_t* sp = s2 + (size_t)b * NT * HID + h;
  const double dsr = (double)D_SR, ssr = (double)S_SR;
  const double dre = (double)D_REF, cr = (double)C_REF;
  double z2 = 0, y2 = 0, zr = 0, yr = 0;
  for (int t = 0; t < NT; t++) {
    y2 = dsr * (y2 + z2);
    z2 = dsr * z2 + r[t];
    double p = ssr * y2;
    yr = dre * (yr + zr);
    double u = p + cr * yr;
    uint8_t s = (u >= 1.0) ? 1 : 0;
    zr = dre * zr + (double)s;
    *sp = s;
    sp += HID;
  }
}

// ---------------- K4: R3[b,o,t] = sum_h w2[o,h] * s2[b,t,h] ----------------
__global__ __launch_bounds__(256) void k4_fc2(const float* __restrict__ w2,
                                              const uint8_t* __restrict__ s2,
                                              double* __restrict__ R3) {
  int id = blockIdx.x * 256 + threadIdx.x;
  if (id >= NB * NOUT * NT) return;
  int t = id % NT;
  int bo = id / NT;                  // b*20 + o
  int o = bo % NOUT;
  int b = bo / NOUT;
  const uint8_t* row = s2 + (size_t)(b * NT + t) * HID;
  const float* wr = w2 + o * HID;
  double acc = 0.0;
#pragma unroll
  for (int h = 0; h < HID; h += 4) {
    uint32_t m = *(const uint32_t*)(row + h);
    float4 w = *(const float4*)(wr + h);
    if (m & 0x000000FFu) acc += (double)w.x;
    if (m & 0x0000FF00u) acc += (double)w.y;
    if (m & 0x00FF0000u) acc += (double)w.z;
    if (m & 0xFF000000u) acc += (double)w.w;
  }
  R3[(size_t)bo * NT + t] = acc;
}

// ---------------- K5: layer-3 psp + spike -> output f32 [b,o,t] ----------------
__global__ __launch_bounds__(256) void k5_out(const double* __restrict__ R3,
                                              float* __restrict__ out) {
  int id = threadIdx.x;
  if (id >= NB * NOUT) return;
  const double* r = R3 + (size_t)id * NT;
  float* orow = out + (size_t)id * NT;
  const double dsr = (double)D_SR, ssr = (double)S_SR;
  const double dre = (double)D_REF, cr = (double)C_REF;
  double z2 = 0, y2 = 0, zr = 0, yr = 0;
  for (int t = 0; t < NT; t++) {
    y2 = dsr * (y2 + z2);
    z2 = dsr * z2 + r[t];
    double p = ssr * y2;
    yr = dre * (yr + zr);
    double u = p + cr * yr;
    float s = (u >= 1.0) ? 1.0f : 0.0f;
    zr = dre * zr + (double)s;
    orow[t] = s;
  }
}

extern "C" void kernel_launch(void* const* d_in, const int* in_sizes, int n_in,
                              void* d_out, int out_size, void* d_ws, size_t ws_size,
                              hipStream_t stream) {
  const float* x  = (const float*)d_in[0];   // [8,6300,500]
  const float* w1 = (const float*)d_in[1];   // [32,6300]
  const float* w2 = (const float*)d_in[2];   // [20,32]
  float* out = (float*)d_out;                // [8,20,500]

  uint8_t* ws = (uint8_t*)d_ws;
  const size_t S1_BYTES = (size_t)NB * NT * F_IN;        // 25,200,000
  const size_t R_BYTES  = (size_t)NB * HID * NT * 8;     // 1,024,000
  const size_t S2_BYTES = (size_t)NB * NT * HID;         // 128,000
  uint8_t* s1 = ws;
  double*  R  = (double*)(ws + S1_BYTES);
  uint8_t* s2 = ws + S1_BYTES + R_BYTES;
  double*  R3 = (double*)(ws + S1_BYTES + R_BYTES + S2_BYTES);

  // K1: layer 1 spikes (exact f32, per-channel)
  k1_layer1<<<(NB * F_IN + 63) / 64, 64, 0, stream>>>(x, s1);
  // K2: fc1 on binary spikes (psp deferred via linearity)
  k2_fc1<<<dim3(NB, (NT + 7) / 8), 256, 0, stream>>>(w1, s1, R);
  // K3: psp-filter + spike for layer 2
  k3_spike2<<<1, 256, 0, stream>>>(R, s2);
  // K4: fc2 on binary spikes
  k4_fc2<<<(NB * NOUT * NT + 255) / 256, 256, 0, stream>>>(w2, s2, R3);
  // K5: psp-filter + spike for layer 3 -> output
  k5_out<<<1, 256, 0, stream>>>(R3, out);
}

// Round 2
// 537.665 us; speedup vs baseline: 1.1935x; 1.1935x over previous
//
#include <hip/hip_runtime.h>
#include <stdint.h>

#define NB 8
#define F_IN 6300
#define NT 500
#define HID 32
#define NOUT 20
#define NW 99   // mask words per (b,t) row: ceil(6300/64)

// float32 constants, rounded exactly as np.float32 would round the doubles
#define D_SR   0.7788007830714049f     // exp(-1/4)
#define S_SR   0.6795704571147613f     // e/4
#define D_REF  0.36787944117144233f    // exp(-1)
#define C_REF  -5.43656365691809f      // -2*e

// ---------------- K0: transpose w1 [32][6300] -> w1t [6300][32] ----------------
__global__ __launch_bounds__(256) void k0_transpose(const float* __restrict__ w1,
                                                    float* __restrict__ w1t) {
  int id = blockIdx.x * 256 + threadIdx.x;   // id = f*32 + o  (coalesced write)
  if (id >= F_IN * HID) return;
  int f = id >> 5, o = id & 31;
  w1t[id] = w1[o * F_IN + f];
}

// ---------------- K1: layer 1 (psp -> spike) exact f32; emits ballot masks ----------------
// One wave per (b, 64-f word). Sequential over t; 15 float4 (60 t) in flight.
__global__ __launch_bounds__(64) void k1_layer1(const float* __restrict__ x,
                                                uint64_t* __restrict__ masks) {
  const int wi = blockIdx.x;          // 0..98
  const int b  = blockIdx.y;
  const int lane = threadIdx.x;
  const int f = wi * 64 + lane;
  const bool valid = f < F_IN;
  const float vm = valid ? 1.0f : 0.0f;
  const float4* xr = (const float4*)(x + ((size_t)b * F_IN + (valid ? f : 0)) * NT);
  uint64_t* mp = masks + (size_t)b * NT * NW + wi;

  float z1 = 0.f, y1 = 0.f, zr = 0.f, yr = 0.f;

  float4 A[5], B[5], C[5];
#pragma unroll
  for (int i = 0; i < 5; i++) A[i] = xr[i];
#pragma unroll
  for (int i = 0; i < 5; i++) B[i] = xr[5 + i];
#pragma unroll
  for (int i = 0; i < 5; i++) C[i] = xr[10 + i];

  for (int g = 0; g < 25; g++) {       // 25 groups x 20 t = 500 t
#pragma unroll
    for (int c = 0; c < 5; c++) {
      float xs[4] = {A[c].x * vm, A[c].y * vm, A[c].z * vm, A[c].w * vm};
#pragma unroll
      for (int e = 0; e < 4; e++) {
        y1 = __fmul_rn(D_SR, __fadd_rn(y1, z1));        // y = d*(y+z)
        z1 = __fadd_rn(__fmul_rn(D_SR, z1), xs[e]);     // z = d*z + x
        float p = __fmul_rn(S_SR, y1);
        yr = __fmul_rn(D_REF, __fadd_rn(yr, zr));
        float u = __fadd_rn(p, __fmul_rn(C_REF, yr));
        bool s = (u >= 1.0f);
        zr = __fadd_rn(__fmul_rn(D_REF, zr), s ? 1.0f : 0.0f);
        uint64_t m = __ballot(s);
        if (lane == 0) *mp = m;
        mp += NW;
      }
    }
#pragma unroll
    for (int i = 0; i < 5; i++) A[i] = B[i];
#pragma unroll
    for (int i = 0; i < 5; i++) B[i] = C[i];
    if (g + 3 < 25) {
      const float4* nxt = xr + (g + 3) * 5;
#pragma unroll
      for (int i = 0; i < 5; i++) C[i] = nxt[i];
    }
  }
}

// ---------------- K2: sparse fc1: R[b,o,t] = sum_{f active} w1t[f][o] (f64) ----------------
// One wave per (b,t); halves of the wave take even/odd mask words; 4 spikes extracted/iter.
__global__ __launch_bounds__(256) void k2_fc1(const float* __restrict__ w1t,
                                              const uint64_t* __restrict__ masks,
                                              double* __restrict__ R) {
  const int lane = threadIdx.x & 63;
  const int wave = threadIdx.x >> 6;
  const int half = lane >> 5;
  const int o = lane & 31;
  const int b = blockIdx.x;
  const int t = blockIdx.y * 4 + wave;        // blockIdx.y 0..124 -> t < 500
  const uint64_t* mrow = masks + (size_t)(b * NT + t) * NW;
  double acc = 0.0;
  for (int wi = half; wi < NW; wi += 2) {
    uint64_t m = mrow[wi];
    const int base = wi * 64;
    while (m) {
      int i0 = __builtin_ctzll(m);  uint64_t m1 = m & (m - 1);
      int i1 = m1 ? __builtin_ctzll(m1) : i0;  uint64_t m2 = m1 ? (m1 & (m1 - 1)) : 0;
      int i2 = m2 ? __builtin_ctzll(m2) : i0;  uint64_t m3 = m2 ? (m2 & (m2 - 1)) : 0;
      int i3 = m3 ? __builtin_ctzll(m3) : i0;  m = m3 ? (m3 & (m3 - 1)) : 0;
      float a0 = w1t[(base + i0) * HID + o];
      float a1 = w1t[(base + i1) * HID + o];
      float a2 = w1t[(base + i2) * HID + o];
      float a3 = w1t[(base + i3) * HID + o];
      acc += (double)a0;
      if (m1) acc += (double)a1;
      if (m2) acc += (double)a2;
      if (m3) acc += (double)a3;
    }
  }
  // combine the two halves (lane ^ 32)
  int hi = __shfl_xor(__double2hiint(acc), 32);
  int lo = __shfl_xor(__double2loint(acc), 32);
  acc += __hiloint2double(hi, lo);
  if (half == 0) R[((size_t)b * HID + o) * NT + t] = acc;
}

// ---------------- K3: layer-2 psp filter + spike -> s2 bytes [b][t][h] ----------------
__global__ __launch_bounds__(256) void k3_spike2(const double* __restrict__ R,
                                                 uint8_t* __restrict__ s2) {
  int id = threadIdx.x;              // NB*HID = 256
  int b = id >> 5, h = id & 31;
  const double* r = R + (size_t)id * NT;
  uint8_t* sp = s2 + (size_t)b * NT * HID + h;
  const double dsr = (double)D_SR, ssr = (double)S_SR;
  const double dre = (double)D_REF, cr = (double)C_REF;
  double z2 = 0, y2 = 0, zr = 0, yr = 0;
  double rb[8];
#pragma unroll
  for (int i = 0; i < 8; i++) rb[i] = r[i];
#pragma unroll 8
  for (int t = 0; t < NT; t++) {
    double ri = rb[t & 7];
    if (t + 8 < NT) rb[t & 7] = r[t + 8];
    y2 = dsr * (y2 + z2);
    z2 = dsr * z2 + ri;
    double p = ssr * y2;
    yr = dre * (yr + zr);
    double u = p + cr * yr;
    uint8_t s = (u >= 1.0) ? 1 : 0;
    zr = dre * zr + (double)s;
    *sp = s;
    sp += HID;
  }
}

// ---------------- K4: R3[b,o,t] = sum_h w2[o,h] * s2[b,t,h] (f64) ----------------
__global__ __launch_bounds__(256) void k4_fc2(const float* __restrict__ w2,
                                              const uint8_t* __restrict__ s2,
                                              double* __restrict__ R3) {
  int id = blockIdx.x * 256 + threadIdx.x;
  if (id >= NB * NOUT * NT) return;
  int t = id % NT;
  int bo = id / NT;
  int o = bo % NOUT;
  int b = bo / NOUT;
  const uint8_t* row = s2 + (size_t)(b * NT + t) * HID;
  const float* wr = w2 + o * HID;
  double acc = 0.0;
#pragma unroll
  for (int h = 0; h < HID; h += 4) {
    uint32_t m = *(const uint32_t*)(row + h);
    float4 w = *(const float4*)(wr + h);
    if (m & 0x000000FFu) acc += (double)w.x;
    if (m & 0x0000FF00u) acc += (double)w.y;
    if (m & 0x00FF0000u) acc += (double)w.z;
    if (m & 0xFF000000u) acc += (double)w.w;
  }
  R3[(size_t)bo * NT + t] = acc;
}

// ---------------- K5: layer-3 psp filter + spike -> output f32 ----------------
__global__ __launch_bounds__(256) void k5_out(const double* __restrict__ R3,
                                              float* __restrict__ out) {
  int id = threadIdx.x;
  if (id >= NB * NOUT) return;
  const double* r = R3 + (size_t)id * NT;
  float* orow = out + (size_t)id * NT;
  const double dsr = (double)D_SR, ssr = (double)S_SR;
  const double dre = (double)D_REF, cr = (double)C_REF;
  double z2 = 0, y2 = 0, zr = 0, yr = 0;
  double rb[8];
#pragma unroll
  for (int i = 0; i < 8; i++) rb[i] = r[i];
#pragma unroll 8
  for (int t = 0; t < NT; t++) {
    double ri = rb[t & 7];
    if (t + 8 < NT) rb[t & 7] = r[t + 8];
    y2 = dsr * (y2 + z2);
    z2 = dsr * z2 + ri;
    double p = ssr * y2;
    yr = dre * (yr + zr);
    double u = p + cr * yr;
    float s = (u >= 1.0) ? 1.0f : 0.0f;
    zr = dre * zr + (double)s;
    orow[t] = s;
  }
}

extern "C" void kernel_launch(void* const* d_in, const int* in_sizes, int n_in,
                              void* d_out, int out_size, void* d_ws, size_t ws_size,
                              hipStream_t stream) {
  const float* x  = (const float*)d_in[0];   // [8,6300,500]
  const float* w1 = (const float*)d_in[1];   // [32,6300]
  const float* w2 = (const float*)d_in[2];   // [20,32]
  float* out = (float*)d_out;                // [8,20,500]

  uint8_t* ws = (uint8_t*)d_ws;
  const size_t W1T_BYTES  = (size_t)F_IN * HID * 4;        //   806,400
  const size_t MASK_BYTES = (size_t)NB * NT * NW * 8;      // 3,168,000
  const size_t R_BYTES    = (size_t)NB * HID * NT * 8;     // 1,024,000
  const size_t S2_BYTES   = (size_t)NB * NT * HID;         //   128,000
  float*    w1t   = (float*)ws;
  uint64_t* masks = (uint64_t*)(ws + W1T_BYTES);
  double*   R     = (double*)(ws + W1T_BYTES + MASK_BYTES);
  uint8_t*  s2    = ws + W1T_BYTES + MASK_BYTES + R_BYTES;
  double*   R3    = (double*)(ws + W1T_BYTES + MASK_BYTES + R_BYTES + S2_BYTES);

  k0_transpose<<<(F_IN * HID + 255) / 256, 256, 0, stream>>>(w1, w1t);
  k1_layer1<<<dim3(NW, NB), 64, 0, stream>>>(x, masks);
  k2_fc1<<<dim3(NB, NT / 4), 256, 0, stream>>>(w1t, masks, R);
  k3_spike2<<<1, 256, 0, stream>>>(R, s2);
  k4_fc2<<<(NB * NOUT * NT + 255) / 256, 256, 0, stream>>>(w2, s2, R3);
  k5_out<<<1, 256, 0, stream>>>(R3, out);
}

// Round 3
// 360.088 us; speedup vs baseline: 1.7821x; 1.4932x over previous
//
#include <hip/hip_runtime.h>
#include <stdint.h>

#define NB 8
#define F_IN 6300
#define NT 500
#define HID 32
#define NOUT 20
#define NW 99   // mask words per (b,t) row: ceil(6300/64)

// float32 constants, rounded exactly as np.float32 would round the doubles
#define D_SR   0.7788007830714049f     // exp(-1/4)
#define S_SR   0.6795704571147613f     // e/4
#define D_REF  0.36787944117144233f    // exp(-1)
#define C_REF  -5.43656365691809f      // -2*e

// ---------------- K0: transpose w1 [32][6300] -> w1t [6300][32] ----------------
__global__ __launch_bounds__(256) void k0_transpose(const float* __restrict__ w1,
                                                    float* __restrict__ w1t) {
  int id = blockIdx.x * 256 + threadIdx.x;   // id = f*32 + o  (coalesced write)
  if (id >= F_IN * HID) return;
  int f = id >> 5, o = id & 31;
  w1t[id] = w1[o * F_IN + f];
}

// ---------------- K1: layer 1 (psp -> spike), exact f32, LDS-staged ----------------
// One wave per (b, 64-f word). 5 chunks of 100 t; global->LDS async DMA, double buffer.
#define CH_T 100
#define CH_I 25   // 16B DMA instructions per chunk (4 t each)

__global__ __launch_bounds__(64) void k1_layer1(const float* __restrict__ x,
                                                uint64_t* __restrict__ masks) {
  __shared__ __align__(16) float lds[2][CH_I][256];  // [buf][j][lane*4+e] = 2 x 25 KB
  const int wi = blockIdx.x;          // 0..98
  const int b  = blockIdx.y;
  const int lane = threadIdx.x;
  int f = wi * 64 + lane;
  const float vm = (f < F_IN) ? 1.0f : 0.0f;
  if (f >= F_IN) f = F_IN - 1;        // clamp: loads stay in-bounds, input zeroed by vm
  const float* xrow = x + ((size_t)b * F_IN + f) * NT;
  uint64_t* mp = masks + (size_t)b * NT * NW + wi;

  float z1 = 0.f, y1 = 0.f, zr = 0.f, yr = 0.f;

  // issue one chunk's DMA: lane i's 16B lands at lds base + i*16
#define ISSUE(chunk, buf)                                                        \
  {                                                                              \
    const float* g = xrow + (chunk) * CH_T;                                      \
    _Pragma("unroll")                                                            \
    for (int j = 0; j < CH_I; j++) {                                             \
      __builtin_amdgcn_global_load_lds(                                          \
          (const __attribute__((address_space(1))) void*)(g + 4 * j),            \
          (__attribute__((address_space(3))) void*)&lds[buf][j][0], 16, 0, 0);   \
    }                                                                            \
  }

  ISSUE(0, 0)
  for (int c = 0; c < 5; c++) {
    if (c + 1 < 5) ISSUE(c + 1, (c + 1) & 1)
    __builtin_amdgcn_s_waitcnt(0);   // drain DMA (next chunk stays resident in LDS B)
    __syncthreads();
    const int buf = c & 1;
#pragma unroll
    for (int j = 0; j < CH_I; j++) {
      float4 v = *(const float4*)&lds[buf][j][lane * 4];
      float xs[4] = {v.x * vm, v.y * vm, v.z * vm, v.w * vm};
#pragma unroll
      for (int e = 0; e < 4; e++) {
        y1 = __fmul_rn(D_SR, __fadd_rn(y1, z1));        // y = d*(y+z)
        z1 = __fadd_rn(__fmul_rn(D_SR, z1), xs[e]);     // z = d*z + x
        float p = __fmul_rn(S_SR, y1);
        yr = __fmul_rn(D_REF, __fadd_rn(yr, zr));
        float u = __fadd_rn(p, __fmul_rn(C_REF, yr));
        bool s = (u >= 1.0f);
        zr = __fadd_rn(__fmul_rn(D_REF, zr), s ? 1.0f : 0.0f);
        uint64_t m = __ballot(s);
        if (lane == 0) *mp = m;
        mp += NW;
      }
    }
    __syncthreads();   // reads drained before this buffer is re-targeted by DMA
  }
#undef ISSUE
}

// ---------------- K2: sparse fc1: R[b,o,t] = sum_{f active} w1t[f][o] (f64) ----------------
__global__ __launch_bounds__(256) void k2_fc1(const float* __restrict__ w1t,
                                              const uint64_t* __restrict__ masks,
                                              double* __restrict__ R) {
  const int lane = threadIdx.x & 63;
  const int wave = threadIdx.x >> 6;
  const int half = lane >> 5;
  const int o = lane & 31;
  const int b = blockIdx.x;
  const int t = blockIdx.y * 4 + wave;        // blockIdx.y 0..124
  const uint64_t* mrow = masks + (size_t)(b * NT + t) * NW;
  double acc = 0.0;
  for (int wi = half; wi < NW; wi += 2) {
    uint64_t m = mrow[wi];
    const int base = wi * 64;
    while (m) {
      int i0 = __builtin_ctzll(m);  uint64_t m1 = m & (m - 1);
      int i1 = m1 ? __builtin_ctzll(m1) : i0;  uint64_t m2 = m1 ? (m1 & (m1 - 1)) : 0;
      int i2 = m2 ? __builtin_ctzll(m2) : i0;  uint64_t m3 = m2 ? (m2 & (m2 - 1)) : 0;
      int i3 = m3 ? __builtin_ctzll(m3) : i0;  m = m3 ? (m3 & (m3 - 1)) : 0;
      float a0 = w1t[(base + i0) * HID + o];
      float a1 = w1t[(base + i1) * HID + o];
      float a2 = w1t[(base + i2) * HID + o];
      float a3 = w1t[(base + i3) * HID + o];
      acc += (double)a0;
      if (m1) acc += (double)a1;
      if (m2) acc += (double)a2;
      if (m3) acc += (double)a3;
    }
  }
  int hi = __shfl_xor(__double2hiint(acc), 32);
  int lo = __shfl_xor(__double2loint(acc), 32);
  acc += __hiloint2double(hi, lo);
  if (half == 0) R[((size_t)b * HID + o) * NT + t] = acc;
}

// ---------------- shared f64 psp+spike step (layers 2/3) ----------------
__device__ __forceinline__ bool snn_step(double ri, double& z2, double& y2,
                                         double& zr, double& yr) {
  const double dsr = (double)D_SR, ssr = (double)S_SR;
  const double dre = (double)D_REF, cr = (double)C_REF;
  y2 = dsr * (y2 + z2);
  z2 = dsr * z2 + ri;
  double p = ssr * y2;
  yr = dre * (yr + zr);
  double u = p + cr * yr;
  bool s = (u >= 1.0);
  zr = dre * zr + (s ? 1.0 : 0.0);
  return s;
}

// ---------------- K3: layer-2 psp filter + spike -> s2 bytes [b][t][h] ----------------
// Static-register prefetch: groups of 4 t (2 x double2), 2 groups in flight.
__global__ __launch_bounds__(256) void k3_spike2(const double* __restrict__ R,
                                                 uint8_t* __restrict__ s2) {
  int id = threadIdx.x;              // NB*HID = 256
  int b = id >> 5, h = id & 31;
  const double2* r2 = (const double2*)(R + (size_t)id * NT);
  uint8_t* sp = s2 + (size_t)b * NT * HID + h;
  double z2 = 0, y2 = 0, zr = 0, yr = 0;
  double2 a0 = r2[0], a1 = r2[1];
  double2 b0 = r2[2], b1 = r2[3];
  for (int g = 0; g < 125; g++) {
    double2 c0, c1;
    if (g + 2 < 125) { c0 = r2[(g + 2) * 2]; c1 = r2[(g + 2) * 2 + 1]; }
    else             { c0 = a0; c1 = a1; }
    sp[0]       = snn_step(a0.x, z2, y2, zr, yr) ? 1 : 0;
    sp[HID]     = snn_step(a0.y, z2, y2, zr, yr) ? 1 : 0;
    sp[2 * HID] = snn_step(a1.x, z2, y2, zr, yr) ? 1 : 0;
    sp[3 * HID] = snn_step(a1.y, z2, y2, zr, yr) ? 1 : 0;
    sp += 4 * HID;
    a0 = b0; a1 = b1; b0 = c0; b1 = c1;
  }
}

// ---------------- K4: R3[b,o,t] = sum_h w2[o,h] * s2[b,t,h] (f64) ----------------
__global__ __launch_bounds__(256) void k4_fc2(const float* __restrict__ w2,
                                              const uint8_t* __restrict__ s2,
                                              double* __restrict__ R3) {
  int id = blockIdx.x * 256 + threadIdx.x;
  if (id >= NB * NOUT * NT) return;
  int t = id % NT;
  int bo = id / NT;
  int o = bo % NOUT;
  int b = bo / NOUT;
  const uint8_t* row = s2 + (size_t)(b * NT + t) * HID;
  const float* wr = w2 + o * HID;
  double acc = 0.0;
#pragma unroll
  for (int h = 0; h < HID; h += 4) {
    uint32_t m = *(const uint32_t*)(row + h);
    float4 w = *(const float4*)(wr + h);
    if (m & 0x000000FFu) acc += (double)w.x;
    if (m & 0x0000FF00u) acc += (double)w.y;
    if (m & 0x00FF0000u) acc += (double)w.z;
    if (m & 0xFF000000u) acc += (double)w.w;
  }
  R3[(size_t)bo * NT + t] = acc;
}

// ---------------- K5: layer-3 psp filter + spike -> output f32 ----------------
__global__ __launch_bounds__(256) void k5_out(const double* __restrict__ R3,
                                              float* __restrict__ out) {
  int id = threadIdx.x;
  if (id >= NB * NOUT) return;
  const double2* r2 = (const double2*)(R3 + (size_t)id * NT);
  float* orow = out + (size_t)id * NT;
  double z2 = 0, y2 = 0, zr = 0, yr = 0;
  double2 a0 = r2[0], a1 = r2[1];
  double2 b0 = r2[2], b1 = r2[3];
  for (int g = 0; g < 125; g++) {
    double2 c0, c1;
    if (g + 2 < 125) { c0 = r2[(g + 2) * 2]; c1 = r2[(g + 2) * 2 + 1]; }
    else             { c0 = a0; c1 = a1; }
    orow[0] = snn_step(a0.x, z2, y2, zr, yr) ? 1.0f : 0.0f;
    orow[1] = snn_step(a0.y, z2, y2, zr, yr) ? 1.0f : 0.0f;
    orow[2] = snn_step(a1.x, z2, y2, zr, yr) ? 1.0f : 0.0f;
    orow[3] = snn_step(a1.y, z2, y2, zr, yr) ? 1.0f : 0.0f;
    orow += 4;
    a0 = b0; a1 = b1; b0 = c0; b1 = c1;
  }
}

extern "C" void kernel_launch(void* const* d_in, const int* in_sizes, int n_in,
                              void* d_out, int out_size, void* d_ws, size_t ws_size,
                              hipStream_t stream) {
  const float* x  = (const float*)d_in[0];   // [8,6300,500]
  const float* w1 = (const float*)d_in[1];   // [32,6300]
  const float* w2 = (const float*)d_in[2];   // [20,32]
  float* out = (float*)d_out;                // [8,20,500]

  uint8_t* ws = (uint8_t*)d_ws;
  const size_t W1T_BYTES  = (size_t)F_IN * HID * 4;        //   806,400
  const size_t MASK_BYTES = (size_t)NB * NT * NW * 8;      // 3,168,000
  const size_t R_BYTES    = (size_t)NB * HID * NT * 8;     // 1,024,000
  const size_t S2_BYTES   = (size_t)NB * NT * HID;         //   128,000
  float*    w1t   = (float*)ws;
  uint64_t* masks = (uint64_t*)(ws + W1T_BYTES);
  double*   R     = (double*)(ws + W1T_BYTES + MASK_BYTES);
  uint8_t*  s2    = ws + W1T_BYTES + MASK_BYTES + R_BYTES;
  double*   R3    = (double*)(ws + W1T_BYTES + MASK_BYTES + R_BYTES + S2_BYTES);

  k0_transpose<<<(F_IN * HID + 255) / 256, 256, 0, stream>>>(w1, w1t);
  k1_layer1<<<dim3(NW, NB), 64, 0, stream>>>(x, masks);
  k2_fc1<<<dim3(NB, NT / 4), 256, 0, stream>>>(w1t, masks, R);
  k3_spike2<<<1, 256, 0, stream>>>(R, s2);
  k4_fc2<<<(NB * NOUT * NT + 255) / 256, 256, 0, stream>>>(w2, s2, R3);
  k5_out<<<1, 256, 0, stream>>>(R3, out);
}